// Round 1
// baseline (99.351 us; speedup 1.0000x reference)
//
#include <hip/hip_runtime.h>
#include <hip/hip_bf16.h>

typedef __attribute__((ext_vector_type(4))) float f32x4;
typedef __attribute__((ext_vector_type(8))) short bf16x8;

#define M_TOT 30752   // 8*62*62 output pixels

__device__ __forceinline__ unsigned short f2bf(float f) {
  unsigned int u = __float_as_uint(f);
  u = u + 0x7FFF + ((u >> 16) & 1);   // round-to-nearest-even
  return (unsigned short)(u >> 16);
}

__device__ __forceinline__ void gload16(const void* g, void* l) {
  __builtin_amdgcn_global_load_lds((const __attribute__((address_space(1))) unsigned int*)g,
                                   (__attribute__((address_space(3))) unsigned int*)l,
                                   16, 0, 0);
}

// ---- prep 1: cast x (fp32) -> bf16, 8 elems/thread ----
__global__ void cast_x(const float* __restrict__ x, unsigned short* __restrict__ xb) {
  int i = blockIdx.x * 256 + threadIdx.x;     // group of 8 floats
  const f32x4* xp = (const f32x4*)x;
  f32x4 a = xp[2 * i];
  f32x4 b = xp[2 * i + 1];
  bf16x8 o;
  o[0] = (short)f2bf(a[0]); o[1] = (short)f2bf(a[1]);
  o[2] = (short)f2bf(a[2]); o[3] = (short)f2bf(a[3]);
  o[4] = (short)f2bf(b[0]); o[5] = (short)f2bf(b[1]);
  o[6] = (short)f2bf(b[2]); o[7] = (short)f2bf(b[3]);
  ((bf16x8*)xb)[i] = o;
}

// ---- prep 2: K_eff[och][kk][f] = sum_bi Q[och,kk,bi] * S[bi*16+(och>>4)][och&15][f]
__global__ void keff_k(const float* __restrict__ Q, const float* __restrict__ S,
                       float* __restrict__ Keff) {
  int bid = blockIdx.x;          // = och*9 + kk, 2304 blocks
  int o = bid / 9;
  int kk = bid - o * 9;
  int f = threadIdx.x;
  int qb = o * 144 + kk * 16;                       // Q[o][kh][kw][bi], kk=kh*3+kw
  int sb = ((o >> 4) * 16 + (o & 15)) * 256 + f;    // S flat base
  float acc = 0.f;
#pragma unroll
  for (int bi = 0; bi < 16; ++bi)
    acc = fmaf(Q[qb + bi], S[sb + bi * 65536], acc);
  Keff[bid * 256 + f] = acc;
}

// ---- prep 3: K2t[kk][f][ci] = sum_o P[o][ci] * Keff[o][kk][f]  (bf16, transposed for LDS)
__global__ void k2t_k(const float* __restrict__ P, const float* __restrict__ Keff,
                      unsigned short* __restrict__ K2t) {
  int kk = blockIdx.x >> 4;            // 0..8
  int f0 = (blockIdx.x & 15) * 16;     // 16 filters per block
  int ci = threadIdx.x;                // 256 threads
  float acc[16];
#pragma unroll
  for (int j = 0; j < 16; ++j) acc[j] = 0.f;
  for (int o = 0; o < 256; ++o) {
    float pv = P[o * 256 + ci];                       // coalesced
    const float* ke = Keff + (o * 9 + kk) * 256 + f0; // broadcast
#pragma unroll
    for (int j = 0; j < 16; ++j) acc[j] = fmaf(pv, ke[j], acc[j]);
  }
#pragma unroll
  for (int j = 0; j < 16; ++j)
    K2t[kk * 65536 + (f0 + j) * 256 + ci] = f2bf(acc[j]);  // coalesced across ci
}

// ---- main: implicit-GEMM conv.  M=30752 (pixels), N=256 (filters), K=2304 (9*256)
// BM=128, BN=256 (full N), BK=64.  8 waves (2m x 4n), each wave 64x64 out.
__global__ __launch_bounds__(512) void conv_gemm(const unsigned short* __restrict__ xb,
                                                 const unsigned short* __restrict__ K2t,
                                                 float* __restrict__ out) {
  __shared__ unsigned short ldsA[128 * 64];   // A tile [row m][k-chunk 64], 16KB, XOR-swizzled
  __shared__ unsigned short ldsB[256 * 64];   // Bt tile [f][k-chunk 64], 32KB, XOR-swizzled

  const int tid = threadIdx.x;
  const int lane = tid & 63;
  const int wm = (tid >> 6) >> 2;   // 0..1
  const int wn = (tid >> 6) & 3;    // 0..3
  const int m0 = blockIdx.x * 128;

  // staging: chunk j covers (row j>>3, 16B slot j&7). Swizzle source so that LDS
  // position p holds data-chunk p ^ (row&7); reader XORs the same way (T2 both-sides).
  const int swslot = (((tid & 7) ^ ((tid >> 3) & 7))) * 8;  // element offset of source chunk
  const int rA = tid >> 3;                                   // A rows rA and rA+64; B rows rA+64q

  int gA0, gA1;
  {
    int m = m0 + rA; if (m >= M_TOT) m = M_TOT - 1;
    int b = m / 3844; int rem = m - b * 3844;
    int h = rem / 62; int w = rem - h * 62;
    gA0 = ((b * 64 + h) * 64 + w) * 256 + swslot;
    m = m0 + rA + 64; if (m >= M_TOT) m = M_TOT - 1;
    b = m / 3844; rem = m - b * 3844;
    h = rem / 62; w = rem - h * 62;
    gA1 = ((b * 64 + h) * 64 + w) * 256 + swslot;
  }

  f32x4 zero = {0.f, 0.f, 0.f, 0.f};
  f32x4 acc[4][4];
#pragma unroll
  for (int i = 0; i < 4; ++i)
#pragma unroll
    for (int j = 0; j < 4; ++j) acc[i][j] = zero;

  const int rl = lane & 15;          // fragment row/col within 16
  const int kg = lane >> 4;          // k-group 0..3
  const int xm = (lane & 7) << 4;    // read-side XOR (row&7)<<4, row&7 == lane&7

  for (int t = 0; t < 36; ++t) {
    int kk = t >> 2;                 // 3x3 tap index
    int cb = t & 3;                  // 64-channel block
    int kh = kk / 3;
    int kw = kk - kh * 3;
    int offA = kh * 16384 + kw * 256 + cb * 64;   // elements into xb
    int offB = kk * 65536 + cb * 64;              // elements into K2t

    gload16(xb + gA0 + offA, &ldsA[tid * 8]);
    gload16(xb + gA1 + offA, &ldsA[(tid + 512) * 8]);
#pragma unroll
    for (int q = 0; q < 4; ++q)
      gload16(K2t + offB + (rA + 64 * q) * 256 + swslot, &ldsB[(tid + 512 * q) * 8]);

    __syncthreads();   // compiler drains vmcnt before barrier -> tile ready

    bf16x8 af[4][2], bfr[4][2];
#pragma unroll
    for (int mi = 0; mi < 4; ++mi) {
      int rb = (wm * 64 + mi * 16 + rl) * 128;
#pragma unroll
      for (int ks = 0; ks < 2; ++ks) {
        int cbyte = (ks * 64 + kg * 16) ^ xm;
        af[mi][ks] = *(const bf16x8*)((const char*)ldsA + rb + cbyte);
      }
    }
#pragma unroll
    for (int ni = 0; ni < 4; ++ni) {
      int rb = (wn * 64 + ni * 16 + rl) * 128;
#pragma unroll
      for (int ks = 0; ks < 2; ++ks) {
        int cbyte = (ks * 64 + kg * 16) ^ xm;
        bfr[ni][ks] = *(const bf16x8*)((const char*)ldsB + rb + cbyte);
      }
    }
#pragma unroll
    for (int ks = 0; ks < 2; ++ks)
#pragma unroll
      for (int mi = 0; mi < 4; ++mi)
#pragma unroll
        for (int ni = 0; ni < 4; ++ni)
          acc[mi][ni] = __builtin_amdgcn_mfma_f32_16x16x32_bf16(
              af[mi][ks], bfr[ni][ks], acc[mi][ni], 0, 0, 0);

    __syncthreads();   // protect LDS from next iteration's staging
  }

  // epilogue: D row = (lane>>4)*4 + r (+16*mi +64*wm), col = lane&15 (+16*ni +64*wn)
#pragma unroll
  for (int mi = 0; mi < 4; ++mi) {
    int mb = m0 + wm * 64 + mi * 16 + kg * 4;
#pragma unroll
    for (int ni = 0; ni < 4; ++ni) {
      int f = wn * 64 + ni * 16 + rl;
#pragma unroll
      for (int r = 0; r < 4; ++r) {
        int m = mb + r;
        if (m < M_TOT) out[m * 256 + f] = acc[mi][ni][r];
      }
    }
  }
}

extern "C" void kernel_launch(void* const* d_in, const int* in_sizes, int n_in,
                              void* d_out, int out_size, void* d_ws, size_t ws_size,
                              hipStream_t stream) {
  const float* x = (const float*)d_in[0];   // [8,64,64,256]
  const float* P = (const float*)d_in[1];   // [256,256]
  const float* Q = (const float*)d_in[2];   // [256,3,3,16]
  const float* S = (const float*)d_in[3];   // [256,16,256]
  float* out = (float*)d_out;               // [8,62,62,256]

  char* ws = (char*)d_ws;
  unsigned short* xb  = (unsigned short*)ws;                         // 16,777,216 B
  float*          Keff = (float*)(ws + 16777216);                    //  2,359,296 B
  unsigned short* K2t = (unsigned short*)(ws + 16777216 + 2359296);  //  1,179,648 B

  cast_x<<<4096, 256, 0, stream>>>(x, xb);
  keff_k<<<2304, 256, 0, stream>>>(Q, S, Keff);
  k2t_k<<<144, 256, 0, stream>>>(P, Keff, K2t);
  conv_gemm<<<241, 512, 0, stream>>>(xb, K2t, out);
}